// Round 7
// baseline (105.583 us; speedup 1.0000x reference)
//
#include <hip/hip_runtime.h>
#include <hip/hip_fp16.h>

// COO SpMM, rows sorted: out[r] = sum_{e: rows[e]==r} vals[e] * embeds[cols[e]]
// N=50000, E=800000, D=64 fp32.
//
// R12: padded interleaved CSR. Evidence: R5->R8 (halve gather instrs, same
// line count) = -4us; R10 (+20k instrs) = +4us; R7 (L2-resident gathers) = no
// gain -> edge-walk cost is per-INSTRUCTION (~90cy/gather), not cache-miss.
// So: minimize instructions + shorten the dependent chain.
//  - setup2 builds a 32-slot/row padded {col,val} array (zeros pad), layout
//    [pair(16 edges)][slot(8)][group-in-pair(2)] so ONE dwordx4/lane feeds
//    2 gather groups -> colval stream instrs halve; vals stream + ALL clamp
//    VALU + tail branches gone.
//  - pair-0 address = r*256 (constant): no row_ptr on the critical path.
//    row_ptr only in the rare deg>32 overflow path (P~1e-4).
//  - empty rows branch-free (zero pad -> gathers row 0 x 0.0).
// Lane map unchanged: slot=lane>>3, f8=lane&7 (16B of 128B fp16 row).
// fp16 embeds staged in d_ws (fp32 accum, absmax 0.0625 << 0.29).

#define D_FEAT 64
#define BLOCK 256
#define PAD_STRIDE 32

// d_ws layout
#define WS_ROWPTR_OFF   0u          // 50001 * 4B
#define WS_CNT_OFF      0x40000u    // 50000 * 4B
#define WS_EMB_OFF      0x80000u    // 6.4MB fp16
#define WS_PAD_OFF      0x700000u   // 50000 * 256B = 12.8MB

typedef float f32x4 __attribute__((ext_vector_type(4)));

// Setup 1: blocks [0, nb_rp) build row_ptr, blocks [nb_rp, ...) f32->f16.
__global__ __launch_bounds__(BLOCK) void setup_fused(
    const int* __restrict__ rows, int* __restrict__ row_ptr,
    const float* __restrict__ embeds, __half* __restrict__ embeds_h,
    int n_nodes, int n_edges, int n4, int nb_rp)
{
    if ((int)blockIdx.x < nb_rp) {
        const int e = blockIdx.x * BLOCK + threadIdx.x;
        if (e >= n_edges) return;
        const int r  = rows[e];
        const int rp = (e == 0) ? -1 : rows[e - 1];
        for (int v = rp + 1; v <= r; ++v) row_ptr[v] = e;
        if (e == n_edges - 1)
            for (int v = r + 1; v <= n_nodes; ++v) row_ptr[v] = n_edges;
    } else {
        const int i = ((int)blockIdx.x - nb_rp) * BLOCK + (int)threadIdx.x;
        if (i >= n4) return;
        const float4 x = ((const float4*)embeds)[i];
        __half2 a = __floats2half2_rn(x.x, x.y);
        __half2 b = __floats2half2_rn(x.z, x.w);
        ((__half2*)embeds_h)[2 * i]     = a;
        ((__half2*)embeds_h)[2 * i + 1] = b;
    }
}

// byte offset of edge-slot k (0..31) within a row's 256B pad block:
// pair p=k>>4 at p*128; slot s=k&7 at s*16; group g=(k>>3)&1 at g*8.
__device__ __forceinline__ int pad_off(int k) {
    return ((k >> 4) << 7) + ((k & 7) << 4) + (((k >> 3) & 1) << 3);
}

// Setup 2: threads [0,n_edges) copy edges into pad; threads
// [n_edges, n_edges+n_nodes) zero the pad tail + write cnt.
__global__ __launch_bounds__(BLOCK) void setup_pad(
    const int* __restrict__ rows,
    const int* __restrict__ cols,
    const float* __restrict__ vals,
    const int* __restrict__ row_ptr,
    char* __restrict__ padb,
    int* __restrict__ cnt,
    int n_nodes, int n_edges)
{
    const int tid = (int)(blockIdx.x * BLOCK + threadIdx.x);
    if (tid < n_edges) {
        const int r = rows[tid];
        const int k = tid - row_ptr[r];
        if (k < PAD_STRIDE) {
            uint2 cv;
            cv.x = (unsigned)cols[tid];
            cv.y = __float_as_uint(vals[tid]);
            *(uint2*)(padb + (size_t)r * 256 + pad_off(k)) = cv;
        }
    } else if (tid < n_edges + n_nodes) {
        const int r = tid - n_edges;
        const int deg = row_ptr[r + 1] - row_ptr[r];
        cnt[r] = (deg + 15) >> 4;   // pairs (0 for empty rows)
        const uint2 z = make_uint2(0u, 0u);
        for (int k = deg; k < PAD_STRIDE; ++k)
            *(uint2*)(padb + (size_t)r * 256 + pad_off(k)) = z;
    }
}

// One wave per row. Pair-0 colval load has NO dependencies (address r*256).
__global__ __launch_bounds__(BLOCK) void spmm_padded(
    const char* __restrict__ padb,
    const int* __restrict__ cnt,
    const int* __restrict__ row_ptr,
    const int* __restrict__ cols,
    const float* __restrict__ vals,
    const __half* __restrict__ embeds_h,
    float* __restrict__ out,
    int n_nodes)
{
    const int r = (int)((blockIdx.x * (unsigned)BLOCK + threadIdx.x) >> 6);
    if (r >= n_nodes) return;
    const int lane = (int)(threadIdx.x & 63u);
    const int slot = lane >> 3;   // edge slot within group
    const int f8   = lane & 7;    // 16B chunk of the 128B fp16 row
    const char* eb0  = (const char*)embeds_h + (f8 << 4);
    const char* rowb = padb + (size_t)r * 256 + (slot << 4);

    float acc[8] = {0.f, 0.f, 0.f, 0.f, 0.f, 0.f, 0.f, 0.f};

#define PROC(COL, VAL)                                                         \
    {                                                                          \
        const float vk = __uint_as_float(VAL);                                 \
        const uint4 p = *(const uint4*)(eb0 + ((size_t)(COL) << 7));           \
        float2 q0 = __half22float2(*(const __half2*)&p.x);                     \
        float2 q1 = __half22float2(*(const __half2*)&p.y);                     \
        float2 q2 = __half22float2(*(const __half2*)&p.z);                     \
        float2 q3 = __half22float2(*(const __half2*)&p.w);                     \
        acc[0] = fmaf(vk, q0.x, acc[0]); acc[1] = fmaf(vk, q0.y, acc[1]);      \
        acc[2] = fmaf(vk, q1.x, acc[2]); acc[3] = fmaf(vk, q1.y, acc[3]);      \
        acc[4] = fmaf(vk, q2.x, acc[4]); acc[5] = fmaf(vk, q2.y, acc[5]);      \
        acc[6] = fmaf(vk, q3.x, acc[6]); acc[7] = fmaf(vk, q3.y, acc[7]);      \
    }

    // pair 0: unconditional, zero-dependency address; covers deg<=16 (57%)
    // and empty rows (zero pad) branch-free.
    const uint4 cv0 = *(const uint4*)(rowb);
    const int nc = cnt[r];
    PROC(cv0.x, cv0.y)
    PROC(cv0.z, cv0.w)

    if (nc > 1) {
        const uint4 cv1 = *(const uint4*)(rowb + 128);
        PROC(cv1.x, cv1.y)
        PROC(cv1.z, cv1.w)
        if (nc > 2) {
            // rare (P ~ 1e-4): deg > 32, finish from original cols/vals
            const int s = row_ptr[r], t = row_ptr[r + 1];
            const int tm1 = t - 1;
            for (int e = s + PAD_STRIDE; e < t; e += 8) {
                const int ik = e + slot;
                const int jk = ik < tm1 ? ik : tm1;
                const unsigned ck = (unsigned)cols[jk];
                float vk = vals[jk];
                if (ik > tm1) vk = 0.f;
                const uint4 p = *(const uint4*)(eb0 + ((size_t)ck << 7));
                float2 q0 = __half22float2(*(const __half2*)&p.x);
                float2 q1 = __half22float2(*(const __half2*)&p.y);
                float2 q2 = __half22float2(*(const __half2*)&p.z);
                float2 q3 = __half22float2(*(const __half2*)&p.w);
                acc[0] = fmaf(vk, q0.x, acc[0]); acc[1] = fmaf(vk, q0.y, acc[1]);
                acc[2] = fmaf(vk, q1.x, acc[2]); acc[3] = fmaf(vk, q1.y, acc[3]);
                acc[4] = fmaf(vk, q2.x, acc[4]); acc[5] = fmaf(vk, q2.y, acc[5]);
                acc[6] = fmaf(vk, q3.x, acc[6]); acc[7] = fmaf(vk, q3.y, acc[7]);
            }
        }
    }
#undef PROC

    // fold the 8 edge slots (xor 8, 16, 32)
#pragma unroll
    for (int i = 0; i < 8; ++i) {
        acc[i] += __shfl_xor(acc[i], 8, 64);
        acc[i] += __shfl_xor(acc[i], 16, 64);
        acc[i] += __shfl_xor(acc[i], 32, 64);
    }

    if (lane < 8) {
        f32x4 v0, v1;
        v0.x = acc[0]; v0.y = acc[1]; v0.z = acc[2]; v0.w = acc[3];
        v1.x = acc[4]; v1.y = acc[5]; v1.z = acc[6]; v1.w = acc[7];
        f32x4* po = (f32x4*)(out + (size_t)r * D_FEAT + (f8 << 3));
        __builtin_nontemporal_store(v0, po);
        __builtin_nontemporal_store(v1, po + 1);
    }
}

extern "C" void kernel_launch(void* const* d_in, const int* in_sizes, int n_in,
                              void* d_out, int out_size, void* d_ws, size_t ws_size,
                              hipStream_t stream) {
    const int*   rows   = (const int*)d_in[0];
    const int*   cols   = (const int*)d_in[1];
    const float* vals   = (const float*)d_in[2];
    const float* embeds = (const float*)d_in[3];
    float*       out    = (float*)d_out;

    const int n_edges = in_sizes[0];
    const int n_nodes = out_size / D_FEAT;
    const int n_feat_total = n_nodes * D_FEAT;   // 3.2M

    int*    row_ptr  = (int*)((char*)d_ws + WS_ROWPTR_OFF);
    int*    cnt      = (int*)((char*)d_ws + WS_CNT_OFF);
    __half* embeds_h = (__half*)((char*)d_ws + WS_EMB_OFF);
    char*   padb     = (char*)d_ws + WS_PAD_OFF;

    {
        const int n4 = n_feat_total / 4;
        const int nb_rp  = (n_edges + BLOCK - 1) / BLOCK;
        const int nb_cvt = (n4 + BLOCK - 1) / BLOCK;
        setup_fused<<<nb_rp + nb_cvt, BLOCK, 0, stream>>>(
            rows, row_ptr, embeds, embeds_h, n_nodes, n_edges, n4, nb_rp);
    }
    {
        const int n_total = n_edges + n_nodes;
        const int nblocks = (n_total + BLOCK - 1) / BLOCK;
        setup_pad<<<nblocks, BLOCK, 0, stream>>>(
            rows, cols, vals, row_ptr, padb, cnt, n_nodes, n_edges);
    }
    {
        const int waves_per_block = BLOCK / 64;
        const int nblocks = (n_nodes + waves_per_block - 1) / waves_per_block;
        spmm_padded<<<nblocks, BLOCK, 0, stream>>>(
            padb, cnt, row_ptr, cols, vals, embeds_h, out, n_nodes);
    }
}

// Round 8
// 95.333 us; speedup vs baseline: 1.1075x; 1.1075x over previous
//
#include <hip/hip_runtime.h>
#include <hip/hip_fp16.h>

// COO SpMM, rows sorted: out[r] = sum_{e: rows[e]==r} vals[e] * embeds[cols[e]]
// N=50000, E=800000, D=64 fp32.
//
// R13 = R8 (best, 94.0us) + __launch_bounds__(256, 8) on the spmm to force
// <=64 VGPR -> 8 waves/SIMD residency (R8 likely sat at 65-128 VGPR -> 4
// waves/SIMD; pool halves at 64/128/256). Theory: spmm (~36us) sits ~1.5-2x
// above its scattered-gather pipe floor (100k gathers x ~150cy / 256 CU =
// 16-25us) because the ~700cy rp->cols->gather chain is under-hidden at 4
// waves/SIMD. Doubling residency should close most of that gap.
// Evidence base: gathers are the ONLY expensive instructions (R5->R8 -4us
// from halving gathers; R12 padding the cheap stream lost; R7 L2-residency
// no gain) -> occupancy is the last untested lever on the R8 shape.
// Lane map: slot=lane>>3 (8 edges/group), f8=lane&7 (16B of the 128B fp16
// row; one gather instr = 8 rows x 128B). deg<=16 fast path = 2 gathers.
// fp16 embeds staged in d_ws (fp32 accum, absmax 0.0625 << 0.29).

#define D_FEAT 64
#define BLOCK 256

typedef float f32x4 __attribute__((ext_vector_type(4)));

// Fused setup: blocks [0, nb_rp) build row_ptr, blocks [nb_rp, ...) do f32->f16.
__global__ __launch_bounds__(BLOCK) void setup_fused(
    const int* __restrict__ rows, int* __restrict__ row_ptr,
    const float* __restrict__ embeds, __half* __restrict__ embeds_h,
    int n_nodes, int n_edges, int n4, int nb_rp)
{
    if ((int)blockIdx.x < nb_rp) {
        const int e = blockIdx.x * BLOCK + threadIdx.x;
        if (e >= n_edges) return;
        const int r  = rows[e];
        const int rp = (e == 0) ? -1 : rows[e - 1];
        for (int v = rp + 1; v <= r; ++v) row_ptr[v] = e;
        if (e == n_edges - 1)
            for (int v = r + 1; v <= n_nodes; ++v) row_ptr[v] = n_edges;
    } else {
        const int i = ((int)blockIdx.x - nb_rp) * BLOCK + (int)threadIdx.x;
        if (i >= n4) return;
        const float4 x = ((const float4*)embeds)[i];
        __half2 a = __floats2half2_rn(x.x, x.y);
        __half2 b = __floats2half2_rn(x.z, x.w);
        ((__half2*)embeds_h)[2 * i]     = a;
        ((__half2*)embeds_h)[2 * i + 1] = b;
    }
}

// One wave per row. lane = slot*8 + f8: slot in [0,8) = edge slot,
// f8 in [0,8) = which 16B chunk (8 halfs) of the 128B fp16 row.
// Tail edges: index clamped to t-1, weight zeroed.
__global__ __launch_bounds__(BLOCK, 8) void spmm_row_f16(
    const int* __restrict__ row_ptr,
    const int* __restrict__ cols,
    const float* __restrict__ vals,
    const __half* __restrict__ embeds_h,
    float* __restrict__ out,
    int n_nodes)
{
    const int wave = (int)((blockIdx.x * (unsigned)BLOCK + threadIdx.x) >> 6);
    if (wave >= n_nodes) return;
    const int lane = (int)(threadIdx.x & 63u);
    const int slot = lane >> 3;   // edge slot 0..7
    const int f8   = lane & 7;    // 16B chunk 0..7

    const int s = row_ptr[wave];
    const int t = row_ptr[wave + 1];

    float acc[8] = {0.f, 0.f, 0.f, 0.f, 0.f, 0.f, 0.f, 0.f};

    const char* eb   = (const char*)embeds_h;
    const int   foff = f8 << 4;           // byte offset of lane's 16B in a row
    const int   tm1  = t - 1;

#define EDGE_GROUP(EBASE, K)                                                   \
    {                                                                          \
        const int ik = (EBASE) + slot + 8 * (K);                               \
        const int jk = ik < tm1 ? ik : tm1;                                    \
        const int ck = cols[jk];                                               \
        float vk = vals[jk];                                                   \
        if (ik > tm1) vk = 0.f;                                                \
        const uint4 p = *(const uint4*)(eb + (((unsigned)ck << 7) + foff));    \
        float2 q0 = __half22float2(*(const __half2*)&p.x);                     \
        float2 q1 = __half22float2(*(const __half2*)&p.y);                     \
        float2 q2 = __half22float2(*(const __half2*)&p.z);                     \
        float2 q3 = __half22float2(*(const __half2*)&p.w);                     \
        acc[0] = fmaf(vk, q0.x, acc[0]); acc[1] = fmaf(vk, q0.y, acc[1]);      \
        acc[2] = fmaf(vk, q1.x, acc[2]); acc[3] = fmaf(vk, q1.y, acc[3]);      \
        acc[4] = fmaf(vk, q2.x, acc[4]); acc[5] = fmaf(vk, q2.y, acc[5]);      \
        acc[6] = fmaf(vk, q3.x, acc[6]); acc[7] = fmaf(vk, q3.y, acc[7]);      \
    }

    if (s < t) {
        if (t - s <= 16) {
            // majority path (deg <= 16): 2 gathers
            EDGE_GROUP(s, 0)
            EDGE_GROUP(s, 1)
        } else {
            for (int e = s; e < t; e += 16) {
                EDGE_GROUP(e, 0)
                EDGE_GROUP(e, 1)
            }
        }
    }
#undef EDGE_GROUP

    // fold the 8 edge slots (xor 8, 16, 32)
#pragma unroll
    for (int i = 0; i < 8; ++i) {
        acc[i] += __shfl_xor(acc[i], 8, 64);
        acc[i] += __shfl_xor(acc[i], 16, 64);
        acc[i] += __shfl_xor(acc[i], 32, 64);
    }

    if (lane < 8) {
        f32x4 r0, r1;
        r0.x = acc[0]; r0.y = acc[1]; r0.z = acc[2]; r0.w = acc[3];
        r1.x = acc[4]; r1.y = acc[5]; r1.z = acc[6]; r1.w = acc[7];
        f32x4* po = (f32x4*)(out + (size_t)wave * D_FEAT + (f8 << 3));
        __builtin_nontemporal_store(r0, po);
        __builtin_nontemporal_store(r1, po + 1);
    }
}

extern "C" void kernel_launch(void* const* d_in, const int* in_sizes, int n_in,
                              void* d_out, int out_size, void* d_ws, size_t ws_size,
                              hipStream_t stream) {
    const int*   rows   = (const int*)d_in[0];
    const int*   cols   = (const int*)d_in[1];
    const float* vals   = (const float*)d_in[2];
    const float* embeds = (const float*)d_in[3];
    float*       out    = (float*)d_out;

    const int n_edges = in_sizes[0];
    const int n_nodes = out_size / D_FEAT;
    const int n_feat_total = n_nodes * D_FEAT;   // 3.2M

    int*    row_ptr  = (int*)d_ws;                               // 50001 ints
    __half* embeds_h = (__half*)((char*)d_ws + (1 << 18));       // 6.4 MB @ 256KB offset

    {
        const int n4 = n_feat_total / 4;
        const int nb_rp  = (n_edges + BLOCK - 1) / BLOCK;
        const int nb_cvt = (n4 + BLOCK - 1) / BLOCK;
        setup_fused<<<nb_rp + nb_cvt, BLOCK, 0, stream>>>(
            rows, row_ptr, embeds, embeds_h, n_nodes, n_edges, n4, nb_rp);
    }
    {
        const int waves_per_block = BLOCK / 64;
        const int nblocks = (n_nodes + waves_per_block - 1) / waves_per_block;
        spmm_row_f16<<<nblocks, BLOCK, 0, stream>>>(
            row_ptr, cols, vals, embeds_h, out, n_nodes);
    }
}